// Round 20
// baseline (373.611 us; speedup 1.0000x reference)
//
#include <hip/hip_runtime.h>
#include <hip/hip_bf16.h>

constexpr int B_ = 2;
constexpr int H_ = 112;
constexpr int W_ = 256;
constexpr int HW_ = H_ * W_;
constexpr int PH_ = 448;   // 4*H
constexpr int PW_ = 1024;  // 4*W
constexpr float EPS_ = 1e-5f;

typedef __bf16 bf16x8 __attribute__((ext_vector_type(8)));
typedef float f32x4 __attribute__((ext_vector_type(4)));

__device__ __forceinline__ bf16x8 ld_bf16x8(const __hip_bfloat16* p) {
    return *reinterpret_cast<const bf16x8*>(p);
}
__device__ __forceinline__ bf16x8 zero_bf16x8() {
    union { int4 i; bf16x8 v; } u;
    u.i = make_int4(0, 0, 0, 0);
    return u.v;
}
// async global->LDS, 16B per lane. LDS dest = wave-uniform base + lane*16.
__device__ __forceinline__ void gload_lds16(const __hip_bfloat16* g, __hip_bfloat16* lds) {
    __builtin_amdgcn_global_load_lds(
        (const __attribute__((address_space(1))) void*)g,
        (__attribute__((address_space(3))) void*)lds, 16, 0, 0);
}

// ---------------------------------------------------------------------------
// Weight prep: (COUT, CSRC, 3, 3) fp32 -> fragment-packed bf16
// layout [tap][ks8][cf=COUT/16][lane64][8]
// ---------------------------------------------------------------------------
__global__ void prep_w3_pack(const float* __restrict__ w, int COUT, int CSRC, int COFF,
                             const float* __restrict__ g, const float* __restrict__ vvar,
                             __hip_bfloat16* __restrict__ dst) {
    int idx = blockIdx.x * 256 + threadIdx.x;
    int CF = COUT / 16;
    int n = 9 * 8 * CF * 512;  // == 9*COUT*256
    if (idx >= n) return;
    int j = idx & 7;
    int lane = (idx >> 3) & 63;
    int rest = idx >> 9;
    int cf = rest % CF;
    int rest2 = rest / CF;
    int ks = rest2 & 7;
    int tap = rest2 >> 3;
    int cout = cf * 16 + (lane & 15);
    int ci = ks * 32 + (lane >> 4) * 8 + j;
    float sc = g ? g[cout] * rsqrtf(vvar[cout] + EPS_) : 1.f;
    dst[idx] = __float2bfloat16(w[((size_t)cout * CSRC + ci + COFF) * 9 + tap] * sc);
}

// c3 pack: (144,512) fp32 -> [ks16][mf9][lane64][8] bf16
__global__ void prep_c3_pack(const float* __restrict__ w, __hip_bfloat16* __restrict__ dst) {
    int idx = blockIdx.x * 256 + threadIdx.x;
    if (idx >= 16 * 9 * 512) return;
    int j = idx & 7;
    int lane = (idx >> 3) & 63;
    int rest = idx >> 9;
    int mf = rest % 9;
    int ks = rest / 9;
    int row = mf * 16 + (lane & 15);
    int ci = ks * 32 + (lane >> 4) * 8 + j;
    dst[idx] = __float2bfloat16(w[(size_t)row * 512 + ci]);
}

// wd_c1 (256x9 fp32, disp-channel weights of c1), bias2 (enc2 folded BN bias)
__global__ void prep_misc_kernel(const float* __restrict__ w_c1,
                                 const float* __restrict__ g, const float* __restrict__ bb,
                                 const float* __restrict__ m, const float* __restrict__ v,
                                 float* __restrict__ wd_c1, float* __restrict__ bias2) {
    int idx = blockIdx.x * 256 + threadIdx.x;
    if (idx < 256 * 9) {
        int co = idx / 9, tap = idx % 9;
        wd_c1[idx] = w_c1[(size_t)co * 257 * 9 + tap];
    } else if (idx < 256 * 9 + 256) {
        int co = idx - 256 * 9;
        float sc = g[co] * rsqrtf(v[co] + EPS_);
        bias2[co] = bb[co] - m[co] * sc;
    }
}

// ---------------------------------------------------------------------------
// enc1: conv(3->256, k=s=4) + BN + ReLU, output NHWC bf16 (B,H,W,256)
// ---------------------------------------------------------------------------
__global__ __launch_bounds__(256) void enc1_nhwc_kernel(
    const float* __restrict__ patch, const float* __restrict__ wgt,
    const float* __restrict__ g, const float* __restrict__ bb,
    const float* __restrict__ m, const float* __restrict__ v,
    __hip_bfloat16* __restrict__ out) {
    const int tid = threadIdx.x;
    const int px = tid & 63;
    const int wid = tid >> 6;
    const int bx = blockIdx.x;
    const int w0 = (bx & 3) * 64;
    const int h = bx >> 2;
    const int b = blockIdx.z;
    const int w = w0 + px;

    float p[3][4][4];
#pragma unroll
    for (int c = 0; c < 3; ++c)
#pragma unroll
        for (int ky = 0; ky < 4; ++ky) {
            float4 f = *reinterpret_cast<const float4*>(
                patch + (((size_t)b * 3 + c) * PH_ + 4 * h + ky) * PW_ + 4 * w);
            p[c][ky][0] = f.x; p[c][ky][1] = f.y; p[c][ky][2] = f.z; p[c][ky][3] = f.w;
        }

    __shared__ __hip_bfloat16 s[64][258];

    const int kbase = __builtin_amdgcn_readfirstlane(wid * 64);
    for (int i = 0; i < 64; ++i) {
        int k = kbase + i;
        const float* wk = wgt + (size_t)k * 48;
        float acc = 0.f;
#pragma unroll
        for (int c = 0; c < 3; ++c)
#pragma unroll
            for (int ky = 0; ky < 4; ++ky)
#pragma unroll
                for (int kx = 0; kx < 4; ++kx)
                    acc += p[c][ky][kx] * wk[(c * 4 + ky) * 4 + kx];
        float sc = g[k] * rsqrtf(v[k] + EPS_);
        float o = fmaxf(acc * sc + (bb[k] - m[k] * sc), 0.f);
        s[px][k] = __float2bfloat16(o);
    }
    __syncthreads();
    const size_t base = (((size_t)b * H_ + h) * W_ + w0) * 256;
    for (int j = tid; j < 64 * 128; j += 256) {
        int elem = j * 2;
        int pp = elem >> 8;
        int k = elem & 255;
        unsigned int val = *reinterpret_cast<const unsigned int*>(&s[pp][k]);
        *reinterpret_cast<unsigned int*>(out + base + elem) = val;
    }
}

// ---------------------------------------------------------------------------
// 3x3 pad-1 conv, CIN=256 NHWC bf16 -> COUT NHWC bf16 via MFMA.
// R20 = R19 with TEPI=true for ALL convs (A/B test: R18's +16us regression
// was {enc2/c1 transposed epilogue} + {c3 32px rewrite} combined; R19
// reverted both. Mechanistically the transposed epilogue should HELP the
// 256-cout convs too (same 8B@512B-stride partial-line store pathology that
// cost c2 ~11us); the c3 rewrite was the likelier culprit. This round
// isolates it: TEPI everywhere, c3 = proven R13 version.)
// Main loop identical to R13/R19: 8 waves, tile 256x128, dbuf LDS,
// zero-cost conflict swizzle, XCD bx swizzle.
// ---------------------------------------------------------------------------
template <int COUT, bool HAS_DISP, bool TEPI>
__global__ __launch_bounds__(512, 4) void conv3x3_swz(
    const __hip_bfloat16* __restrict__ in,     // (B,H,W,256)
    const __hip_bfloat16* __restrict__ wPack,  // packed per prep_w3_pack
    const float* __restrict__ bias,            // (COUT)
    const float* __restrict__ disp,            // (B,H,W) or null
    const float* __restrict__ wd,              // (COUT,9) or null
    __hip_bfloat16* __restrict__ out) {        // (B,H,W,COUT)
    constexpr int CIN = 256;
    constexpr int CF = COUT / 16;
    const int tid = threadIdx.x;
    const int lane = tid & 63;
    const int wid = tid >> 6;   // 0..7
    const int wm = wid & 3;     // cout quarter
    const int wn = wid >> 2;    // px half
    const int lr = lane & 15;
    const int lg = lane >> 4;

    // XCD-aware swizzle of bx (224 tiles = 8 XCDs x 28)
    int bx = blockIdx.x;
    bx = (bx & 7) * 28 + (bx >> 3);
    const int w0 = (bx & 1) * 128;
    const int h = bx >> 1;
    const int coutBase = blockIdx.y * 256;
    const int b = blockIdx.z;

    const int coutW = coutBase + wm * 64;
    const int cfW = coutW >> 4;
    const int pxW = wn * 64;  // block-local

    __shared__ __hip_bfloat16 sIn[2][3][130][32];  // 49,920 B

    f32x4 acc[4][4] = {};

    const __hip_bfloat16* inb = in + (size_t)b * HW_ * CIN;
    const __hip_bfloat16* wBase = wPack + (size_t)cfW * 512 + (size_t)lane * 8;

    // per-lane swizzled read offsets (bytes), one per kx
    const int key0 = (lr >> 1) & 3;
    const int key1 = ((lr + 1) >> 1) & 3;
    const int key2 = (key0 + 1) & 3;
    const int loff0 = lr * 64 + ((lg ^ key0) << 4);
    const int loff1 = lr * 64 + ((lg ^ key1) << 4);
    const int loff2 = lr * 64 + ((lg ^ key2) << 4);

    // staging source-chunk permutation: inverse swizzle on the global source
    const int key_w = (((lane >> 2) + 1) >> 1) & 3;
    const int csw = (((lane & 3) ^ key_w)) * 8;

    auto STAGE = [&](int buf, int c0) {
        // main: px 1..128, 24 wave-units (3 rows x 8 groups of 16 px)
#pragma unroll
        for (int i = 0; i < 3; ++i) {
            const int idx = wid * 3 + i;
            const int row = idx >> 3, grp = idx & 7;
            const int y = h + row - 1;
            __hip_bfloat16* ldsb = &sIn[buf][row][1 + grp * 16][0];
            if ((unsigned)y < (unsigned)H_) {
                const __hip_bfloat16* gp = inb +
                    ((size_t)y * W_ + w0 + grp * 16 + (lane >> 2)) * CIN + c0 + csw;
                gload_lds16(gp, ldsb);
            } else {
                *reinterpret_cast<int4*>(reinterpret_cast<char*>(ldsb) + lane * 16) =
                    make_int4(0, 0, 0, 0);
            }
        }
        // tail: px 0 and 129 (halo), key = 0 -> direct slots
        if (tid < 24) {
            const int row = tid >> 3, p2 = (tid >> 2) & 1, sub = tid & 3;
            const int pxl = p2 ? 129 : 0;
            const int y = h + row - 1, x = w0 + pxl - 1;
            bf16x8 v = zero_bf16x8();
            if ((unsigned)y < (unsigned)H_ && (unsigned)x < (unsigned)W_)
                v = ld_bf16x8(inb + ((size_t)y * W_ + x) * CIN + c0 + sub * 8);
            *reinterpret_cast<bf16x8*>(&sIn[buf][row][pxl][sub * 8]) = v;
        }
    };

    STAGE(0, 0);
    __syncthreads();
    int cur = 0;
    for (int ks = 0; ks < 8; ++ks) {
        if (ks < 7) STAGE(cur ^ 1, (ks + 1) * 32);
        const char* sB = reinterpret_cast<const char*>(&sIn[cur][0][0][0]) + pxW * 64;
#pragma unroll
        for (int tap = 0; tap < 9; ++tap) {
            const int ky = tap / 3, kx = tap % 3;
            const int lofk = (kx == 0) ? loff0 : (kx == 1) ? loff1 : loff2;
            bf16x8 a[4];
#pragma unroll
            for (int mf = 0; mf < 4; ++mf)
                a[mf] = ld_bf16x8(wBase + ((size_t)(tap * 8 + ks) * CF + mf) * 512);
            bf16x8 bv[4];
#pragma unroll
            for (int nf = 0; nf < 4; ++nf)
                bv[nf] = *reinterpret_cast<const bf16x8*>(
                    sB + ky * 8320 + (nf * 16 + kx) * 64 + lofk);
            __builtin_amdgcn_s_setprio(1);
#pragma unroll
            for (int nf = 0; nf < 4; ++nf)
#pragma unroll
                for (int mf = 0; mf < 4; ++mf)
                    acc[mf][nf] = __builtin_amdgcn_mfma_f32_16x16x32_bf16(
                        a[mf], bv[nf], acc[mf][nf], 0, 0, 0);
            __builtin_amdgcn_s_setprio(0);
        }
        __syncthreads();  // drains next-chunk global_load_lds + syncs LDS readers
        cur ^= 1;
    }

    const size_t rowBase = ((size_t)b * H_ + h) * W_;

    if (!TEPI) {
        // ---- direct epilogue (R13): bias (+disp) + ReLU, uint2 NHWC store
#pragma unroll
        for (int nf = 0; nf < 4; ++nf) {
            const int px = w0 + pxW + nf * 16 + lr;
            float dnb[9];
            if (HAS_DISP) {
#pragma unroll
                for (int t = 0; t < 9; ++t) {
                    int yy = h + t / 3 - 1, xx = px + t % 3 - 1;
                    dnb[t] = ((unsigned)yy < (unsigned)H_ && (unsigned)xx < (unsigned)W_)
                                 ? disp[((size_t)b * H_ + yy) * W_ + xx]
                                 : 0.f;
                }
            }
#pragma unroll
            for (int mf = 0; mf < 4; ++mf) {
                alignas(8) __hip_bfloat16 ov[4];
#pragma unroll
                for (int r = 0; r < 4; ++r) {
                    const int cout = coutW + mf * 16 + lg * 4 + r;
                    float o = acc[mf][nf][r] + bias[cout];
                    if (HAS_DISP) {
                        float s = 0.f;
#pragma unroll
                        for (int t = 0; t < 9; ++t) s += wd[cout * 9 + t] * dnb[t];
                        o += s;
                    }
                    ov[r] = __float2bfloat16(fmaxf(o, 0.f));
                }
                *reinterpret_cast<uint2*>(out + (rowBase + px) * COUT + coutW + mf * 16 + lg * 4) =
                    *reinterpret_cast<const uint2*>(ov);
            }
        }
    } else {
        // ---- transposed epilogue: LDS [64 px][264 ch] scratch,
        //      two px-half rounds, fully-coalesced 16B stores
        __hip_bfloat16* sOut = &sIn[0][0][0][0];  // 33,792 B <= 49,920 B
#pragma unroll 1
        for (int r2 = 0; r2 < 2; ++r2) {
            if (wn == r2) {
#pragma unroll
                for (int nf = 0; nf < 4; ++nf) {
                    const int pxl = nf * 16 + lr;          // 0..63 local
                    const int px = w0 + r2 * 64 + pxl;     // global W index
                    float dnb[9];
                    if (HAS_DISP) {
#pragma unroll
                        for (int t = 0; t < 9; ++t) {
                            int yy = h + t / 3 - 1, xx = px + t % 3 - 1;
                            dnb[t] = ((unsigned)yy < (unsigned)H_ && (unsigned)xx < (unsigned)W_)
                                         ? disp[((size_t)b * H_ + yy) * W_ + xx]
                                         : 0.f;
                        }
                    }
#pragma unroll
                    for (int mf = 0; mf < 4; ++mf) {
                        alignas(8) __hip_bfloat16 ov[4];
#pragma unroll
                        for (int r = 0; r < 4; ++r) {
                            const int cout = coutW + mf * 16 + lg * 4 + r;
                            float o = acc[mf][nf][r] + bias[cout];
                            if (HAS_DISP) {
                                float s = 0.f;
#pragma unroll
                                for (int t = 0; t < 9; ++t) s += wd[cout * 9 + t] * dnb[t];
                                o += s;
                            }
                            ov[r] = __float2bfloat16(fmaxf(o, 0.f));
                        }
                        const int cl = wm * 64 + mf * 16 + lg * 4;  // block-local cout
                        *reinterpret_cast<uint2*>(&sOut[pxl * 264 + cl]) =
                            *reinterpret_cast<const uint2*>(ov);
                    }
                }
            }
            __syncthreads();
            // coalesced store: 64 px x 256 couts, 16B per thread-chunk
            for (int j = tid; j < 64 * 32; j += 512) {
                const int pxl = j >> 5, ch = j & 31;
                bf16x8 v = *reinterpret_cast<const bf16x8*>(&sOut[pxl * 264 + ch * 8]);
                *reinterpret_cast<bf16x8*>(
                    out + (rowBase + w0 + r2 * 64 + pxl) * COUT + coutBase + ch * 8) = v;
            }
            __syncthreads();  // protect next round's sOut writes
        }
    }
}

// ---------------------------------------------------------------------------
// c3 (1x1, 512->144) + softmax(9) + unfold(disp) + 4x upsample, fused.
// R13 version (proven): 16 px/wave, grid (H*4, 1, B), 256 thr.
// cout = mf*16+st: mf = tap, st = lg*4+r -> softmax lane-local, float4 store.
// ---------------------------------------------------------------------------
__global__ __launch_bounds__(256) void c3_fused_kernel(
    const __hip_bfloat16* __restrict__ x2,     // (B,H,W,512)
    const __hip_bfloat16* __restrict__ wPack,  // [ks16][mf9][lane64][8]
    const float* __restrict__ bias,            // (144)
    const float* __restrict__ disp,            // (B,H,W)
    float* __restrict__ outp) {                // (B,1,4H,4W)
    const int tid = threadIdx.x;
    const int lane = tid & 63;
    const int wid = tid >> 6;
    const int lr = lane & 15;
    const int lg = lane >> 4;
    const int bx = blockIdx.x;
    const int w0 = (bx & 3) * 64;
    const int h = bx >> 2;
    const int b = blockIdx.z;
    const int pxw = w0 + wid * 16 + lr;

    f32x4 acc[9] = {};
    const __hip_bfloat16* inp = x2 + (((size_t)b * H_ + h) * W_ + pxw) * 512;
    const __hip_bfloat16* wl = wPack + (size_t)lane * 8;
#pragma unroll 4
    for (int ks = 0; ks < 16; ++ks) {
        const int c0 = ks * 32 + lg * 8;
        bf16x8 bv = ld_bf16x8(inp + c0);
#pragma unroll
        for (int mf = 0; mf < 9; ++mf) {
            bf16x8 av = ld_bf16x8(wl + ((size_t)ks * 9 + mf) * 512);
            acc[mf] = __builtin_amdgcn_mfma_f32_16x16x32_bf16(av, bv, acc[mf], 0, 0, 0);
        }
    }

    float dnb[9];
#pragma unroll
    for (int t = 0; t < 9; ++t) {
        int yy = h + t / 3 - 1, xx = pxw + t % 3 - 1;
        dnb[t] = ((unsigned)yy < (unsigned)H_ && (unsigned)xx < (unsigned)W_)
                     ? disp[((size_t)b * H_ + yy) * W_ + xx]
                     : 0.f;
    }
    float oo[4];
#pragma unroll
    for (int r = 0; r < 4; ++r) {
        const int st = lg * 4 + r;
        float sv[9], mx = -1e30f;
#pragma unroll
        for (int mf = 0; mf < 9; ++mf) {
            sv[mf] = acc[mf][r] + bias[mf * 16 + st];
            mx = fmaxf(mx, sv[mf]);
        }
        float sum = 0.f, wsum = 0.f;
#pragma unroll
        for (int mf = 0; mf < 9; ++mf) {
            float e = __expf(sv[mf] - mx);
            sum += e;
            wsum += e * dnb[mf];
        }
        oo[r] = wsum / sum;
    }
    float4 o4 = make_float4(oo[0], oo[1], oo[2], oo[3]);
    *reinterpret_cast<float4*>(outp + ((size_t)b * PH_ + 4 * h + lg) * PW_ + 4 * pxw) = o4;
}

// ---------------------------------------------------------------------------
extern "C" void kernel_launch(void* const* d_in, const int* in_sizes, int n_in,
                              void* d_out, int out_size, void* d_ws, size_t ws_size,
                              hipStream_t stream) {
    const float* patch = (const float*)d_in[0];
    const float* disp = (const float*)d_in[1];
    const float* w_enc1 = (const float*)d_in[2];
    const float* bn1_g = (const float*)d_in[3];
    const float* bn1_b = (const float*)d_in[4];
    const float* bn1_m = (const float*)d_in[5];
    const float* bn1_v = (const float*)d_in[6];
    const float* w_enc2 = (const float*)d_in[7];
    const float* bn2_g = (const float*)d_in[8];
    const float* bn2_b = (const float*)d_in[9];
    const float* bn2_m = (const float*)d_in[10];
    const float* bn2_v = (const float*)d_in[11];
    const float* w_c1 = (const float*)d_in[12];
    const float* b_c1 = (const float*)d_in[13];
    const float* w_c2 = (const float*)d_in[14];
    const float* b_c2 = (const float*)d_in[15];
    const float* w_c3 = (const float*)d_in[16];
    const float* b_c3 = (const float*)d_in[17];
    float* out = (float*)d_out;

    char* ws = (char*)d_ws;
    const size_t S1 = (size_t)B_ * HW_ * 256 * sizeof(__hip_bfloat16);  // 29.36 MB
    const size_t S2 = (size_t)B_ * HW_ * 512 * sizeof(__hip_bfloat16);  // 58.72 MB
    __hip_bfloat16* feat1 = (__hip_bfloat16*)ws;   ws += S1;
    __hip_bfloat16* feat2 = (__hip_bfloat16*)ws;   ws += S1;
    __hip_bfloat16* x1    = (__hip_bfloat16*)ws;   ws += S1;
    __hip_bfloat16* x2    = (__hip_bfloat16*)ws;   ws += S2;
    __hip_bfloat16* wP_enc2 = (__hip_bfloat16*)ws; ws += (size_t)9 * 256 * 256 * 2;
    __hip_bfloat16* wP_c1   = (__hip_bfloat16*)ws; ws += (size_t)9 * 256 * 256 * 2;
    __hip_bfloat16* wP_c2   = (__hip_bfloat16*)ws; ws += (size_t)9 * 512 * 256 * 2;
    __hip_bfloat16* wP_c3   = (__hip_bfloat16*)ws; ws += (size_t)16 * 9 * 512 * 2;
    float* bias2 = (float*)ws;                     ws += 256 * 4;
    float* wd_c1 = (float*)ws;                     ws += 256 * 9 * 4;

    dim3 blk(256, 1, 1);
    dim3 blk2(512, 1, 1);

    prep_w3_pack<<<dim3((9 * 256 * 256 + 255) / 256), blk, 0, stream>>>(
        w_enc2, 256, 256, 0, bn2_g, bn2_v, wP_enc2);
    prep_w3_pack<<<dim3((9 * 256 * 256 + 255) / 256), blk, 0, stream>>>(
        w_c1, 256, 257, 1, nullptr, nullptr, wP_c1);
    prep_w3_pack<<<dim3((9 * 512 * 256 + 255) / 256), blk, 0, stream>>>(
        w_c2, 512, 256, 0, nullptr, nullptr, wP_c2);
    prep_c3_pack<<<dim3((16 * 9 * 512 + 255) / 256), blk, 0, stream>>>(w_c3, wP_c3);
    prep_misc_kernel<<<dim3((256 * 9 + 256 + 255) / 256), blk, 0, stream>>>(
        w_c1, bn2_g, bn2_b, bn2_m, bn2_v, wd_c1, bias2);

    // 1. enc1 -> feat1 (NHWC bf16)
    enc1_nhwc_kernel<<<dim3(H_ * 4, 1, B_), blk, 0, stream>>>(
        patch, w_enc1, bn1_g, bn1_b, bn1_m, bn1_v, feat1);
    // 2. enc2 -> feat2 (transposed epilogue)
    conv3x3_swz<256, false, true><<<dim3(2 * H_, 1, B_), blk2, 0, stream>>>(
        feat1, wP_enc2, bias2, nullptr, nullptr, feat2);
    // 3. c1 (+disp channel) -> x1 (transposed epilogue)
    conv3x3_swz<256, true, true><<<dim3(2 * H_, 1, B_), blk2, 0, stream>>>(
        feat2, wP_c1, b_c1, disp, wd_c1, x1);
    // 4. c2 -> x2 (transposed epilogue)
    conv3x3_swz<512, false, true><<<dim3(2 * H_, 2, B_), blk2, 0, stream>>>(
        x1, wP_c2, b_c2, nullptr, nullptr, x2);
    // 5. c3 + softmax + unfold + upsample -> out
    c3_fused_kernel<<<dim3(H_ * 4, 1, B_), blk, 0, stream>>>(
        x2, wP_c3, b_c3, disp, out);
}

// Round 21
// 353.643 us; speedup vs baseline: 1.0565x; 1.0565x over previous
//
#include <hip/hip_runtime.h>
#include <hip/hip_bf16.h>

constexpr int B_ = 2;
constexpr int H_ = 112;
constexpr int W_ = 256;
constexpr int HW_ = H_ * W_;
constexpr int PH_ = 448;   // 4*H
constexpr int PW_ = 1024;  // 4*W
constexpr float EPS_ = 1e-5f;

typedef __bf16 bf16x8 __attribute__((ext_vector_type(8)));
typedef float f32x4 __attribute__((ext_vector_type(4)));

__device__ __forceinline__ bf16x8 ld_bf16x8(const __hip_bfloat16* p) {
    return *reinterpret_cast<const bf16x8*>(p);
}
__device__ __forceinline__ bf16x8 zero_bf16x8() {
    union { int4 i; bf16x8 v; } u;
    u.i = make_int4(0, 0, 0, 0);
    return u.v;
}
// async global->LDS, 16B per lane. LDS dest = wave-uniform base + lane*16.
__device__ __forceinline__ void gload_lds16(const __hip_bfloat16* g, __hip_bfloat16* lds) {
    __builtin_amdgcn_global_load_lds(
        (const __attribute__((address_space(1))) void*)g,
        (__attribute__((address_space(3))) void*)lds, 16, 0, 0);
}

// ---------------------------------------------------------------------------
// Weight prep: (COUT, CSRC, 3, 3) fp32 -> fragment-packed bf16
// layout [tap][ks8][cf=COUT/16][lane64][8]
// ---------------------------------------------------------------------------
__global__ void prep_w3_pack(const float* __restrict__ w, int COUT, int CSRC, int COFF,
                             const float* __restrict__ g, const float* __restrict__ vvar,
                             __hip_bfloat16* __restrict__ dst) {
    int idx = blockIdx.x * 256 + threadIdx.x;
    int CF = COUT / 16;
    int n = 9 * 8 * CF * 512;  // == 9*COUT*256
    if (idx >= n) return;
    int j = idx & 7;
    int lane = (idx >> 3) & 63;
    int rest = idx >> 9;
    int cf = rest % CF;
    int rest2 = rest / CF;
    int ks = rest2 & 7;
    int tap = rest2 >> 3;
    int cout = cf * 16 + (lane & 15);
    int ci = ks * 32 + (lane >> 4) * 8 + j;
    float sc = g ? g[cout] * rsqrtf(vvar[cout] + EPS_) : 1.f;
    dst[idx] = __float2bfloat16(w[((size_t)cout * CSRC + ci + COFF) * 9 + tap] * sc);
}

// c3 pack: (144,512) fp32 -> [ks16][mf9][lane64][8] bf16
__global__ void prep_c3_pack(const float* __restrict__ w, __hip_bfloat16* __restrict__ dst) {
    int idx = blockIdx.x * 256 + threadIdx.x;
    if (idx >= 16 * 9 * 512) return;
    int j = idx & 7;
    int lane = (idx >> 3) & 63;
    int rest = idx >> 9;
    int mf = rest % 9;
    int ks = rest / 9;
    int row = mf * 16 + (lane & 15);
    int ci = ks * 32 + (lane >> 4) * 8 + j;
    dst[idx] = __float2bfloat16(w[(size_t)row * 512 + ci]);
}

// wd_c1 (256x9 fp32, disp-channel weights of c1), bias2 (enc2 folded BN bias)
__global__ void prep_misc_kernel(const float* __restrict__ w_c1,
                                 const float* __restrict__ g, const float* __restrict__ bb,
                                 const float* __restrict__ m, const float* __restrict__ v,
                                 float* __restrict__ wd_c1, float* __restrict__ bias2) {
    int idx = blockIdx.x * 256 + threadIdx.x;
    if (idx < 256 * 9) {
        int co = idx / 9, tap = idx % 9;
        wd_c1[idx] = w_c1[(size_t)co * 257 * 9 + tap];
    } else if (idx < 256 * 9 + 256) {
        int co = idx - 256 * 9;
        float sc = g[co] * rsqrtf(v[co] + EPS_);
        bias2[co] = bb[co] - m[co] * sc;
    }
}

// ---------------------------------------------------------------------------
// enc1: conv(3->256, k=s=4) + BN + ReLU, output NHWC bf16 (B,H,W,256)
// ---------------------------------------------------------------------------
__global__ __launch_bounds__(256) void enc1_nhwc_kernel(
    const float* __restrict__ patch, const float* __restrict__ wgt,
    const float* __restrict__ g, const float* __restrict__ bb,
    const float* __restrict__ m, const float* __restrict__ v,
    __hip_bfloat16* __restrict__ out) {
    const int tid = threadIdx.x;
    const int px = tid & 63;
    const int wid = tid >> 6;
    const int bx = blockIdx.x;
    const int w0 = (bx & 3) * 64;
    const int h = bx >> 2;
    const int b = blockIdx.z;
    const int w = w0 + px;

    float p[3][4][4];
#pragma unroll
    for (int c = 0; c < 3; ++c)
#pragma unroll
        for (int ky = 0; ky < 4; ++ky) {
            float4 f = *reinterpret_cast<const float4*>(
                patch + (((size_t)b * 3 + c) * PH_ + 4 * h + ky) * PW_ + 4 * w);
            p[c][ky][0] = f.x; p[c][ky][1] = f.y; p[c][ky][2] = f.z; p[c][ky][3] = f.w;
        }

    __shared__ __hip_bfloat16 s[64][258];

    const int kbase = __builtin_amdgcn_readfirstlane(wid * 64);
    for (int i = 0; i < 64; ++i) {
        int k = kbase + i;
        const float* wk = wgt + (size_t)k * 48;
        float acc = 0.f;
#pragma unroll
        for (int c = 0; c < 3; ++c)
#pragma unroll
            for (int ky = 0; ky < 4; ++ky)
#pragma unroll
                for (int kx = 0; kx < 4; ++kx)
                    acc += p[c][ky][kx] * wk[(c * 4 + ky) * 4 + kx];
        float sc = g[k] * rsqrtf(v[k] + EPS_);
        float o = fmaxf(acc * sc + (bb[k] - m[k] * sc), 0.f);
        s[px][k] = __float2bfloat16(o);
    }
    __syncthreads();
    const size_t base = (((size_t)b * H_ + h) * W_ + w0) * 256;
    for (int j = tid; j < 64 * 128; j += 256) {
        int elem = j * 2;
        int pp = elem >> 8;
        int k = elem & 255;
        unsigned int val = *reinterpret_cast<const unsigned int*>(&s[pp][k]);
        *reinterpret_cast<unsigned int*>(out + base + elem) = val;
    }
}

// ---------------------------------------------------------------------------
// 3x3 pad-1 conv, CIN=256 NHWC bf16 -> COUT NHWC bf16 via MFMA.
// R21 = R19 exact restore (best measured: 354.6 us).
//   TEPI=true  (c2, COUT=512): LDS-transposed coalesced stores.
//   TEPI=false (enc2/c1, COUT=256): direct uint2 stores (R20 proved the
//              transposed epilogue costs +9us each on 256-cout convs).
// Main loop: 8 waves, tile 256x128, dbuf LDS, zero-cost conflict swizzle,
// XCD bx swizzle.
// ---------------------------------------------------------------------------
template <int COUT, bool HAS_DISP, bool TEPI>
__global__ __launch_bounds__(512, 4) void conv3x3_swz(
    const __hip_bfloat16* __restrict__ in,     // (B,H,W,256)
    const __hip_bfloat16* __restrict__ wPack,  // packed per prep_w3_pack
    const float* __restrict__ bias,            // (COUT)
    const float* __restrict__ disp,            // (B,H,W) or null
    const float* __restrict__ wd,              // (COUT,9) or null
    __hip_bfloat16* __restrict__ out) {        // (B,H,W,COUT)
    constexpr int CIN = 256;
    constexpr int CF = COUT / 16;
    const int tid = threadIdx.x;
    const int lane = tid & 63;
    const int wid = tid >> 6;   // 0..7
    const int wm = wid & 3;     // cout quarter
    const int wn = wid >> 2;    // px half
    const int lr = lane & 15;
    const int lg = lane >> 4;

    // XCD-aware swizzle of bx (224 tiles = 8 XCDs x 28)
    int bx = blockIdx.x;
    bx = (bx & 7) * 28 + (bx >> 3);
    const int w0 = (bx & 1) * 128;
    const int h = bx >> 1;
    const int coutBase = blockIdx.y * 256;
    const int b = blockIdx.z;

    const int coutW = coutBase + wm * 64;
    const int cfW = coutW >> 4;
    const int pxW = wn * 64;  // block-local

    __shared__ __hip_bfloat16 sIn[2][3][130][32];  // 49,920 B

    f32x4 acc[4][4] = {};

    const __hip_bfloat16* inb = in + (size_t)b * HW_ * CIN;
    const __hip_bfloat16* wBase = wPack + (size_t)cfW * 512 + (size_t)lane * 8;

    // per-lane swizzled read offsets (bytes), one per kx
    const int key0 = (lr >> 1) & 3;
    const int key1 = ((lr + 1) >> 1) & 3;
    const int key2 = (key0 + 1) & 3;
    const int loff0 = lr * 64 + ((lg ^ key0) << 4);
    const int loff1 = lr * 64 + ((lg ^ key1) << 4);
    const int loff2 = lr * 64 + ((lg ^ key2) << 4);

    // staging source-chunk permutation: inverse swizzle on the global source
    const int key_w = (((lane >> 2) + 1) >> 1) & 3;
    const int csw = (((lane & 3) ^ key_w)) * 8;

    auto STAGE = [&](int buf, int c0) {
        // main: px 1..128, 24 wave-units (3 rows x 8 groups of 16 px)
#pragma unroll
        for (int i = 0; i < 3; ++i) {
            const int idx = wid * 3 + i;
            const int row = idx >> 3, grp = idx & 7;
            const int y = h + row - 1;
            __hip_bfloat16* ldsb = &sIn[buf][row][1 + grp * 16][0];
            if ((unsigned)y < (unsigned)H_) {
                const __hip_bfloat16* gp = inb +
                    ((size_t)y * W_ + w0 + grp * 16 + (lane >> 2)) * CIN + c0 + csw;
                gload_lds16(gp, ldsb);
            } else {
                *reinterpret_cast<int4*>(reinterpret_cast<char*>(ldsb) + lane * 16) =
                    make_int4(0, 0, 0, 0);
            }
        }
        // tail: px 0 and 129 (halo), key = 0 -> direct slots
        if (tid < 24) {
            const int row = tid >> 3, p2 = (tid >> 2) & 1, sub = tid & 3;
            const int pxl = p2 ? 129 : 0;
            const int y = h + row - 1, x = w0 + pxl - 1;
            bf16x8 v = zero_bf16x8();
            if ((unsigned)y < (unsigned)H_ && (unsigned)x < (unsigned)W_)
                v = ld_bf16x8(inb + ((size_t)y * W_ + x) * CIN + c0 + sub * 8);
            *reinterpret_cast<bf16x8*>(&sIn[buf][row][pxl][sub * 8]) = v;
        }
    };

    STAGE(0, 0);
    __syncthreads();
    int cur = 0;
    for (int ks = 0; ks < 8; ++ks) {
        if (ks < 7) STAGE(cur ^ 1, (ks + 1) * 32);
        const char* sB = reinterpret_cast<const char*>(&sIn[cur][0][0][0]) + pxW * 64;
#pragma unroll
        for (int tap = 0; tap < 9; ++tap) {
            const int ky = tap / 3, kx = tap % 3;
            const int lofk = (kx == 0) ? loff0 : (kx == 1) ? loff1 : loff2;
            bf16x8 a[4];
#pragma unroll
            for (int mf = 0; mf < 4; ++mf)
                a[mf] = ld_bf16x8(wBase + ((size_t)(tap * 8 + ks) * CF + mf) * 512);
            bf16x8 bv[4];
#pragma unroll
            for (int nf = 0; nf < 4; ++nf)
                bv[nf] = *reinterpret_cast<const bf16x8*>(
                    sB + ky * 8320 + (nf * 16 + kx) * 64 + lofk);
            __builtin_amdgcn_s_setprio(1);
#pragma unroll
            for (int nf = 0; nf < 4; ++nf)
#pragma unroll
                for (int mf = 0; mf < 4; ++mf)
                    acc[mf][nf] = __builtin_amdgcn_mfma_f32_16x16x32_bf16(
                        a[mf], bv[nf], acc[mf][nf], 0, 0, 0);
            __builtin_amdgcn_s_setprio(0);
        }
        __syncthreads();  // drains next-chunk global_load_lds + syncs LDS readers
        cur ^= 1;
    }

    const size_t rowBase = ((size_t)b * H_ + h) * W_;

    if (!TEPI) {
        // ---- direct epilogue (R13): bias (+disp) + ReLU, uint2 NHWC store
#pragma unroll
        for (int nf = 0; nf < 4; ++nf) {
            const int px = w0 + pxW + nf * 16 + lr;
            float dnb[9];
            if (HAS_DISP) {
#pragma unroll
                for (int t = 0; t < 9; ++t) {
                    int yy = h + t / 3 - 1, xx = px + t % 3 - 1;
                    dnb[t] = ((unsigned)yy < (unsigned)H_ && (unsigned)xx < (unsigned)W_)
                                 ? disp[((size_t)b * H_ + yy) * W_ + xx]
                                 : 0.f;
                }
            }
#pragma unroll
            for (int mf = 0; mf < 4; ++mf) {
                alignas(8) __hip_bfloat16 ov[4];
#pragma unroll
                for (int r = 0; r < 4; ++r) {
                    const int cout = coutW + mf * 16 + lg * 4 + r;
                    float o = acc[mf][nf][r] + bias[cout];
                    if (HAS_DISP) {
                        float s = 0.f;
#pragma unroll
                        for (int t = 0; t < 9; ++t) s += wd[cout * 9 + t] * dnb[t];
                        o += s;
                    }
                    ov[r] = __float2bfloat16(fmaxf(o, 0.f));
                }
                *reinterpret_cast<uint2*>(out + (rowBase + px) * COUT + coutW + mf * 16 + lg * 4) =
                    *reinterpret_cast<const uint2*>(ov);
            }
        }
    } else {
        // ---- transposed epilogue (R18): LDS [64 px][264 ch] scratch,
        //      two px-half rounds, fully-coalesced 16B stores
        __hip_bfloat16* sOut = &sIn[0][0][0][0];  // 33,792 B <= 49,920 B
#pragma unroll 1
        for (int r2 = 0; r2 < 2; ++r2) {
            if (wn == r2) {
#pragma unroll
                for (int nf = 0; nf < 4; ++nf) {
                    const int pxl = nf * 16 + lr;          // 0..63 local
                    const int px = w0 + r2 * 64 + pxl;     // global W index
                    float dnb[9];
                    if (HAS_DISP) {
#pragma unroll
                        for (int t = 0; t < 9; ++t) {
                            int yy = h + t / 3 - 1, xx = px + t % 3 - 1;
                            dnb[t] = ((unsigned)yy < (unsigned)H_ && (unsigned)xx < (unsigned)W_)
                                         ? disp[((size_t)b * H_ + yy) * W_ + xx]
                                         : 0.f;
                        }
                    }
#pragma unroll
                    for (int mf = 0; mf < 4; ++mf) {
                        alignas(8) __hip_bfloat16 ov[4];
#pragma unroll
                        for (int r = 0; r < 4; ++r) {
                            const int cout = coutW + mf * 16 + lg * 4 + r;
                            float o = acc[mf][nf][r] + bias[cout];
                            if (HAS_DISP) {
                                float s = 0.f;
#pragma unroll
                                for (int t = 0; t < 9; ++t) s += wd[cout * 9 + t] * dnb[t];
                                o += s;
                            }
                            ov[r] = __float2bfloat16(fmaxf(o, 0.f));
                        }
                        const int cl = wm * 64 + mf * 16 + lg * 4;  // block-local cout
                        *reinterpret_cast<uint2*>(&sOut[pxl * 264 + cl]) =
                            *reinterpret_cast<const uint2*>(ov);
                    }
                }
            }
            __syncthreads();
            // coalesced store: 64 px x 256 couts, 16B per thread-chunk
            for (int j = tid; j < 64 * 32; j += 512) {
                const int pxl = j >> 5, ch = j & 31;
                bf16x8 v = *reinterpret_cast<const bf16x8*>(&sOut[pxl * 264 + ch * 8]);
                *reinterpret_cast<bf16x8*>(
                    out + (rowBase + w0 + r2 * 64 + pxl) * COUT + coutBase + ch * 8) = v;
            }
            __syncthreads();  // protect next round's sOut writes
        }
    }
}

// ---------------------------------------------------------------------------
// c3 (1x1, 512->144) + softmax(9) + unfold(disp) + 4x upsample, fused.
// R13 version (proven): 16 px/wave, grid (H*4, 1, B), 256 thr.
// cout = mf*16+st: mf = tap, st = lg*4+r -> softmax lane-local, float4 store.
// ---------------------------------------------------------------------------
__global__ __launch_bounds__(256) void c3_fused_kernel(
    const __hip_bfloat16* __restrict__ x2,     // (B,H,W,512)
    const __hip_bfloat16* __restrict__ wPack,  // [ks16][mf9][lane64][8]
    const float* __restrict__ bias,            // (144)
    const float* __restrict__ disp,            // (B,H,W)
    float* __restrict__ outp) {                // (B,1,4H,4W)
    const int tid = threadIdx.x;
    const int lane = tid & 63;
    const int wid = tid >> 6;
    const int lr = lane & 15;
    const int lg = lane >> 4;
    const int bx = blockIdx.x;
    const int w0 = (bx & 3) * 64;
    const int h = bx >> 2;
    const int b = blockIdx.z;
    const int pxw = w0 + wid * 16 + lr;

    f32x4 acc[9] = {};
    const __hip_bfloat16* inp = x2 + (((size_t)b * H_ + h) * W_ + pxw) * 512;
    const __hip_bfloat16* wl = wPack + (size_t)lane * 8;
#pragma unroll 4
    for (int ks = 0; ks < 16; ++ks) {
        const int c0 = ks * 32 + lg * 8;
        bf16x8 bv = ld_bf16x8(inp + c0);
#pragma unroll
        for (int mf = 0; mf < 9; ++mf) {
            bf16x8 av = ld_bf16x8(wl + ((size_t)ks * 9 + mf) * 512);
            acc[mf] = __builtin_amdgcn_mfma_f32_16x16x32_bf16(av, bv, acc[mf], 0, 0, 0);
        }
    }

    float dnb[9];
#pragma unroll
    for (int t = 0; t < 9; ++t) {
        int yy = h + t / 3 - 1, xx = pxw + t % 3 - 1;
        dnb[t] = ((unsigned)yy < (unsigned)H_ && (unsigned)xx < (unsigned)W_)
                     ? disp[((size_t)b * H_ + yy) * W_ + xx]
                     : 0.f;
    }
    float oo[4];
#pragma unroll
    for (int r = 0; r < 4; ++r) {
        const int st = lg * 4 + r;
        float sv[9], mx = -1e30f;
#pragma unroll
        for (int mf = 0; mf < 9; ++mf) {
            sv[mf] = acc[mf][r] + bias[mf * 16 + st];
            mx = fmaxf(mx, sv[mf]);
        }
        float sum = 0.f, wsum = 0.f;
#pragma unroll
        for (int mf = 0; mf < 9; ++mf) {
            float e = __expf(sv[mf] - mx);
            sum += e;
            wsum += e * dnb[mf];
        }
        oo[r] = wsum / sum;
    }
    float4 o4 = make_float4(oo[0], oo[1], oo[2], oo[3]);
    *reinterpret_cast<float4*>(outp + ((size_t)b * PH_ + 4 * h + lg) * PW_ + 4 * pxw) = o4;
}

// ---------------------------------------------------------------------------
extern "C" void kernel_launch(void* const* d_in, const int* in_sizes, int n_in,
                              void* d_out, int out_size, void* d_ws, size_t ws_size,
                              hipStream_t stream) {
    const float* patch = (const float*)d_in[0];
    const float* disp = (const float*)d_in[1];
    const float* w_enc1 = (const float*)d_in[2];
    const float* bn1_g = (const float*)d_in[3];
    const float* bn1_b = (const float*)d_in[4];
    const float* bn1_m = (const float*)d_in[5];
    const float* bn1_v = (const float*)d_in[6];
    const float* w_enc2 = (const float*)d_in[7];
    const float* bn2_g = (const float*)d_in[8];
    const float* bn2_b = (const float*)d_in[9];
    const float* bn2_m = (const float*)d_in[10];
    const float* bn2_v = (const float*)d_in[11];
    const float* w_c1 = (const float*)d_in[12];
    const float* b_c1 = (const float*)d_in[13];
    const float* w_c2 = (const float*)d_in[14];
    const float* b_c2 = (const float*)d_in[15];
    const float* w_c3 = (const float*)d_in[16];
    const float* b_c3 = (const float*)d_in[17];
    float* out = (float*)d_out;

    char* ws = (char*)d_ws;
    const size_t S1 = (size_t)B_ * HW_ * 256 * sizeof(__hip_bfloat16);  // 29.36 MB
    const size_t S2 = (size_t)B_ * HW_ * 512 * sizeof(__hip_bfloat16);  // 58.72 MB
    __hip_bfloat16* feat1 = (__hip_bfloat16*)ws;   ws += S1;
    __hip_bfloat16* feat2 = (__hip_bfloat16*)ws;   ws += S1;
    __hip_bfloat16* x1    = (__hip_bfloat16*)ws;   ws += S1;
    __hip_bfloat16* x2    = (__hip_bfloat16*)ws;   ws += S2;
    __hip_bfloat16* wP_enc2 = (__hip_bfloat16*)ws; ws += (size_t)9 * 256 * 256 * 2;
    __hip_bfloat16* wP_c1   = (__hip_bfloat16*)ws; ws += (size_t)9 * 256 * 256 * 2;
    __hip_bfloat16* wP_c2   = (__hip_bfloat16*)ws; ws += (size_t)9 * 512 * 256 * 2;
    __hip_bfloat16* wP_c3   = (__hip_bfloat16*)ws; ws += (size_t)16 * 9 * 512 * 2;
    float* bias2 = (float*)ws;                     ws += 256 * 4;
    float* wd_c1 = (float*)ws;                     ws += 256 * 9 * 4;

    dim3 blk(256, 1, 1);
    dim3 blk2(512, 1, 1);

    prep_w3_pack<<<dim3((9 * 256 * 256 + 255) / 256), blk, 0, stream>>>(
        w_enc2, 256, 256, 0, bn2_g, bn2_v, wP_enc2);
    prep_w3_pack<<<dim3((9 * 256 * 256 + 255) / 256), blk, 0, stream>>>(
        w_c1, 256, 257, 1, nullptr, nullptr, wP_c1);
    prep_w3_pack<<<dim3((9 * 512 * 256 + 255) / 256), blk, 0, stream>>>(
        w_c2, 512, 256, 0, nullptr, nullptr, wP_c2);
    prep_c3_pack<<<dim3((16 * 9 * 512 + 255) / 256), blk, 0, stream>>>(w_c3, wP_c3);
    prep_misc_kernel<<<dim3((256 * 9 + 256 + 255) / 256), blk, 0, stream>>>(
        w_c1, bn2_g, bn2_b, bn2_m, bn2_v, wd_c1, bias2);

    // 1. enc1 -> feat1 (NHWC bf16)
    enc1_nhwc_kernel<<<dim3(H_ * 4, 1, B_), blk, 0, stream>>>(
        patch, w_enc1, bn1_g, bn1_b, bn1_m, bn1_v, feat1);
    // 2. enc2 -> feat2 (direct epilogue)
    conv3x3_swz<256, false, false><<<dim3(2 * H_, 1, B_), blk2, 0, stream>>>(
        feat1, wP_enc2, bias2, nullptr, nullptr, feat2);
    // 3. c1 (+disp channel) -> x1 (direct epilogue)
    conv3x3_swz<256, true, false><<<dim3(2 * H_, 1, B_), blk2, 0, stream>>>(
        feat2, wP_c1, b_c1, disp, wd_c1, x1);
    // 4. c2 -> x2 (transposed coalesced epilogue)
    conv3x3_swz<512, false, true><<<dim3(2 * H_, 2, B_), blk2, 0, stream>>>(
        x1, wP_c2, b_c2, nullptr, nullptr, x2);
    // 5. c3 + softmax + unfold + upsample -> out
    c3_fused_kernel<<<dim3(H_ * 4, 1, B_), blk, 0, stream>>>(
        x2, wP_c3, b_c3, disp, out);
}